// Round 9
// baseline (344.724 us; speedup 1.0000x reference)
//
#include <hip/hip_runtime.h>
#include <hip/hip_bf16.h>

// NeRF coarse renderer. Layer 2 on bf16 MFMA:
//   rows 0-47:  h2 = Ah*Bh                       (1-term, err ~sqrt2*2^-9, rgb-smooth)
//   rows 48-63: h2 = Ah*(Bh+Bl) + Al*Bh          (3-term — sample 63 feeds the
//                                                 alpha = 1-exp(-1e10*relu(sigma)) STEP)
// Layer 3 on MFMA (wave-K-split, W3 B-frag cols 0-3 real), partials reduced via
// LDS atomicAdd. sigma_63 recomputed exactly from f32-staged h2 row 63.
// 1 ray/block, LDS 40960 B => 4 blocks/CU (32 waves, max occupancy).
//
// d_in: 0 near(B,1) 1 far(B,1) 2 center(B,3) 3 dir(B,3)
//       4 W1(3,256) 5 b1(256) 6 W2(256,256) 7 b2(256) 8 W3(256,4) 9 b3(4)
// d_out: [rgb (B,3) | depth (B) | weights (B,64) | sigmas_last (B)] f32
// d_ws: W2 repacked as MFMA B-fragments, bf16 hi[64K] + lo[64K] (256 KiB).

constexpr int H  = 256;
constexpr int KS = 64;     // samples per ray = M rows per block

typedef __attribute__((ext_vector_type(8))) short short8;           // 8 bf16
typedef __attribute__((ext_vector_type(4))) float f32x4;            // C/D frag

__device__ __forceinline__ f32x4 mfma16(short8 a, short8 b, f32x4 c) {
    return __builtin_amdgcn_mfma_f32_16x16x32_bf16(a, b, c, 0, 0, 0);
}
__device__ __forceinline__ void split_bf16(float x, short& hi, short& lo) {
    __hip_bfloat16 h = __float2bfloat16(x);
    float hf = __bfloat162float(h);
    __hip_bfloat16 l = __float2bfloat16(x - hf);
    union { __hip_bfloat16 b; short s; } c1, c2;
    c1.b = h; c2.b = l;
    hi = c1.s; lo = c2.s;
}
__device__ __forceinline__ unsigned short f2bf(float x) {
    union { __hip_bfloat16 b; unsigned short s; } c;
    c.b = __float2bfloat16(x);
    return c.s;
}
__device__ __forceinline__ float bf2f(unsigned short s) {
    union { unsigned int u; float f; } c;
    c.u = ((unsigned int)s) << 16;
    return c.f;
}

// ---- pre-pass: pack W2 (f32 row-major [k][n]) into frag-ordered bf16 hi/lo.
// Element i = ((ks*16 + ntg)*64 + lane)*8 + e  maps to
//   k = ks*32 + (lane>>4)*8 + e,  n = ntg*16 + (lane&15).
__global__ void pack_w2_kernel(const float* __restrict__ W2,
                               unsigned short* __restrict__ hi,
                               unsigned short* __restrict__ lo)
{
    const int i  = blockIdx.x * 256 + threadIdx.x;   // 0..65535
    const int e  = i & 7;
    const int l  = (i >> 3) & 63;
    const int nt = (i >> 9) & 15;
    const int ks = i >> 13;
    const int k  = ks * 32 + (l >> 4) * 8 + e;
    const int n  = nt * 16 + (l & 15);
    short h, lw;
    split_bf16(W2[k * H + n], h, lw);
    hi[i] = (unsigned short)h;
    lo[i] = (unsigned short)lw;
}

// LDS, lifetime-aliased, 40960 B total => 4 blocks/CU:
//   big (32 KiB): ah A-frags (ph1->ph2)  ALIASES  h2f layer-3 A-frags (ph3->ph4)
//   r2  ( 8 KiB): al3 lo A-frags mt3 (ph1->ph2)  ALIASES  comb[64][4]+row63[256] (ph3->ph5)
struct R2a { unsigned short al3[8 * 64 * 8]; };          // 8 KiB
struct R2b { float comb[KS][4]; float row63[H]; };       // 1 KiB + 1 KiB
union  R2  { R2a a; R2b b; };
struct SM {
    union { unsigned short ah[8 * 4 * 64 * 8];
            unsigned short h2f[8 * 4 * 64 * 8]; } big;   // 32 KiB
    R2 r2;                                               //  8 KiB
};

__launch_bounds__(512, 8)
__global__ void nerf_mfma_kernel(
    const float* __restrict__ g_near, const float* __restrict__ g_far,
    const float* __restrict__ g_center, const float* __restrict__ g_dir,
    const float* __restrict__ W1, const float* __restrict__ b1,
    const float* __restrict__ b2,
    const float* __restrict__ W3, const float* __restrict__ b3,
    const unsigned short* __restrict__ w2h, const unsigned short* __restrict__ w2l,
    float* __restrict__ out, int B)
{
    __shared__ __align__(16) SM sm;

    const int t    = threadIdx.x;
    const int lane = t & 63;
    const int wv   = __builtin_amdgcn_readfirstlane(t >> 6);   // 0..7
    const int r    = blockIdx.x;                               // ray id

    // ---- ray params (block-uniform scalar loads) ----
    const float nr = g_near[r], fa = g_far[r];
    const float cx = g_center[r*3+0], cy = g_center[r*3+1], cz = g_center[r*3+2];
    const float dx = g_dir[r*3+0],    dy = g_dir[r*3+1],    dz = g_dir[r*3+2];

    // ---- phase 1: layer 1 (f32, points recomputed in-register);
    //      h1 -> bf16 A-frags (hi; +lo for mt==3) ----
    {
        const int kbase = wv * 32 + (lane >> 4) * 8;   // 8 consecutive k
        float w1r[3][8], b1r[8];
        #pragma unroll
        for (int c = 0; c < 3; ++c) {
            const f32x4 a = *(const f32x4*)&W1[c * H + kbase];
            const f32x4 b = *(const f32x4*)&W1[c * H + kbase + 4];
            #pragma unroll
            for (int e = 0; e < 4; ++e) { w1r[c][e] = a[e]; w1r[c][e+4] = b[e]; }
        }
        {
            const f32x4 a = *(const f32x4*)&b1[kbase];
            const f32x4 b = *(const f32x4*)&b1[kbase + 4];
            #pragma unroll
            for (int e = 0; e < 4; ++e) { b1r[e] = a[e]; b1r[e+4] = b[e]; }
        }
        const int prow = lane & 15;
        #pragma unroll
        for (int mt = 0; mt < 4; ++mt) {
            const int srow = mt * 16 + prow;
            const float uu = (float)srow * (1.0f / 63.0f);
            const float z  = nr * (1.0f - uu) + fa * uu;
            const float px = cx + z * dx, py = cy + z * dy, pz = cz + z * dz;
            short8 hv, lv;
            #pragma unroll
            for (int e = 0; e < 8; ++e) {
                float x = fmaf(px, w1r[0][e],
                          fmaf(py, w1r[1][e],
                          fmaf(pz, w1r[2][e], b1r[e])));
                x = fmaxf(x, 0.0f);
                const unsigned short hb = f2bf(x);
                hv[e] = (short)hb;
                if (mt == 3) lv[e] = (short)f2bf(x - bf2f(hb));
            }
            *(short8*)&sm.big.ah[((wv * 4 + mt) * 64 + lane) * 8] = hv;
            if (mt == 3) *(short8*)&sm.r2.a.al3[(wv * 64 + lane) * 8] = lv;
        }
    }
    __syncthreads();

    // ---- phase 2: layer 2 GEMM via MFMA (1-term; mt3 = 3-term) ----
    f32x4 acc[4][2];
    #pragma unroll
    for (int mt = 0; mt < 4; ++mt) {
        acc[mt][0] = (f32x4){0.f,0.f,0.f,0.f};
        acc[mt][1] = (f32x4){0.f,0.f,0.f,0.f};
    }
    {
        const int ntg0 = wv * 2, ntg1 = ntg0 + 1;
        const short8* Bh = (const short8*)w2h;
        const short8* Bl = (const short8*)w2l;
        const short8* Ah = (const short8*)sm.big.ah;
        const short8* Al = (const short8*)sm.r2.a.al3;
        __builtin_amdgcn_s_setprio(1);
        #pragma unroll 2
        for (int ks = 0; ks < 8; ++ks) {
            const short8 b0h  = Bh[(ks * 16 + ntg0) * 64 + lane];
            const short8 b1h_ = Bh[(ks * 16 + ntg1) * 64 + lane];
            #pragma unroll
            for (int mt = 0; mt < 4; ++mt) {
                const short8 ah = Ah[(ks * 4 + mt) * 64 + lane];
                f32x4 c0 = acc[mt][0], c1 = acc[mt][1];
                c0 = mfma16(ah, b0h, c0);
                c1 = mfma16(ah, b1h_, c1);
                if (mt == 3) {               // sigma-critical rows: full 3-term
                    const short8 b0l = Bl[(ks * 16 + ntg0) * 64 + lane];
                    const short8 b1l = Bl[(ks * 16 + ntg1) * 64 + lane];
                    const short8 al  = Al[ks * 64 + lane];
                    c0 = mfma16(ah, b0l, c0);
                    c0 = mfma16(al, b0h, c0);
                    c1 = mfma16(ah, b1l, c1);
                    c1 = mfma16(al, b1h_, c1);
                }
                acc[mt][0] = c0; acc[mt][1] = c1;
            }
        }
        __builtin_amdgcn_s_setprio(0);
    }
    __syncthreads();   // ah/al3 dead; big->h2f, r2->comb/row63 reuse is now safe

    // ---- phase 3: zero comb; +b2, ReLU; h2 -> bf16 A-frag order; row 63 f32 ----
    if (t < 256) ((float*)sm.r2.b.comb)[t] = 0.0f;
    {
        const int c0 = wv * 32 + (lane & 15);
        const int c1 = c0 + 16;
        const float b2c0 = b2[c0], b2c1 = b2[c1];
        const int rlow = (lane >> 4) * 4;
        const int jj0 = lane & 15, jj1 = jj0 + 16;
        const bool lastGrp = ((lane >> 4) == 3);
        #pragma unroll
        for (int mt = 0; mt < 4; ++mt) {
            const f32x4 v0 = acc[mt][0], v1 = acc[mt][1];
            #pragma unroll
            for (int q = 0; q < 4; ++q) {
                const float a0 = fmaxf(v0[q] + b2c0, 0.0f);
                const float a1 = fmaxf(v1[q] + b2c1, 0.0f);
                const int l20 = ((jj0 >> 3) << 4) | (rlow + q);
                const int l21 = ((jj1 >> 3) << 4) | (rlow + q);
                sm.big.h2f[((wv * 4 + mt) * 64 + l20) * 8 + (jj0 & 7)] = f2bf(a0);
                sm.big.h2f[((wv * 4 + mt) * 64 + l21) * 8 + (jj1 & 7)] = f2bf(a1);
                if (mt == 3 && lastGrp && q == 3) {
                    sm.r2.b.row63[c0] = a0; sm.r2.b.row63[c1] = a1;
                }
            }
        }
    }
    __syncthreads();

    // ---- phase 4: layer 3 via MFMA, K-split across waves; reduce via ds_add ----
    {
        // W3 B-frag on the fly: k = wv*32 + (lane>>4)*8 + e, n = lane&15 (<4 real)
        const int n = lane & 15;
        short8 bw3;
        #pragma unroll
        for (int e = 0; e < 8; ++e) {
            const int k = wv * 32 + (lane >> 4) * 8 + e;
            const float v = (n < 4) ? W3[k * 4 + n] : 0.0f;
            bw3[e] = (short)f2bf(v);
        }
        const short8* Ah2 = (const short8*)sm.big.h2f;
        #pragma unroll
        for (int mt = 0; mt < 4; ++mt) {
            const short8 a = Ah2[(wv * 4 + mt) * 64 + lane];
            f32x4 d = (f32x4){0.f,0.f,0.f,0.f};
            d = mfma16(a, bw3, d);
            if (n < 4) {
                #pragma unroll
                for (int q = 0; q < 4; ++q)
                    atomicAdd(&sm.r2.b.comb[mt * 16 + (lane >> 4) * 4 + q][n], d[q]);
            }
        }
    }
    __syncthreads();

    // ---- phase 5: volume rendering (wave 0, lane = sample) ----
    if (t < KS) {
        const int s = t;

        // exact sigma for sample 63: all 64 lanes cooperate on the 256-dot
        float sp = 0.f;
        #pragma unroll
        for (int q = 0; q < 4; ++q) {
            const int j = s * 4 + q;
            sp = fmaf(sm.r2.b.row63[j], W3[j * 4 + 3], sp);
        }
        #pragma unroll
        for (int off = 32; off > 0; off >>= 1) sp += __shfl_xor(sp, off, 64);
        const float sig63 = sp + b3[3];

        const f32x4 cc = *(const f32x4*)&sm.r2.b.comb[s][0];
        const float o0 = cc[0] + b3[0];
        const float o1 = cc[1] + b3[1];
        const float o2 = cc[2] + b3[2];
        const float sigma = (s == 63) ? sig63 : (cc[3] + b3[3]);

        const float uu = (float)s * (1.0f / 63.0f);
        const float z  = nr * (1.0f - uu) + fa * uu;
        const float u2 = (float)(s + 1) * (1.0f / 63.0f);
        const float z2 = nr * (1.0f - u2) + fa * u2;
        const float delta = (s == 63) ? 1e10f : (z2 - z);
        const float alpha = 1.0f - __expf(-delta * fmaxf(sigma, 0.0f));

        // exclusive product scan of (1 - alpha + eps)
        float P = 1.0f - alpha + 1e-8f;
        #pragma unroll
        for (int off = 1; off < 64; off <<= 1) {
            const float v = __shfl_up(P, off, 64);
            if (s >= off) P *= v;
        }
        float T = __shfl_up(P, 1, 64);
        if (s == 0) T = 1.0f;
        const float w = alpha * T;

        out[(size_t)B * 4 + (size_t)r * 64 + s] = w;

        float ws = w, dep = w * z, q0 = w * o0, q1 = w * o1, q2 = w * o2;
        #pragma unroll
        for (int off = 32; off > 0; off >>= 1) {
            ws  += __shfl_xor(ws,  off, 64);
            dep += __shfl_xor(dep, off, 64);
            q0  += __shfl_xor(q0,  off, 64);
            q1  += __shfl_xor(q1,  off, 64);
            q2  += __shfl_xor(q2,  off, 64);
        }
        if (s == 0) {
            out[(size_t)r * 3 + 0] = q0 + 1.0f - ws;
            out[(size_t)r * 3 + 1] = q1 + 1.0f - ws;
            out[(size_t)r * 3 + 2] = q2 + 1.0f - ws;
            out[(size_t)B * 3 + r] = dep;
            out[(size_t)B * 68 + r] = sig63;
        }
    }
}

extern "C" void kernel_launch(void* const* d_in, const int* in_sizes, int n_in,
                              void* d_out, int out_size, void* d_ws, size_t ws_size,
                              hipStream_t stream)
{
    const int B = in_sizes[0];
    if (ws_size < (size_t)(2 * 65536 * sizeof(unsigned short))) return;  // need 256 KiB

    unsigned short* w2h = (unsigned short*)d_ws;
    unsigned short* w2l = w2h + 65536;

    pack_w2_kernel<<<256, 256, 0, stream>>>((const float*)d_in[6], w2h, w2l);

    nerf_mfma_kernel<<<B, 512, 0, stream>>>(
        (const float*)d_in[0], (const float*)d_in[1],
        (const float*)d_in[2], (const float*)d_in[3],
        (const float*)d_in[4], (const float*)d_in[5],
        (const float*)d_in[7],
        (const float*)d_in[8], (const float*)d_in[9],
        w2h, w2l,
        (float*)d_out, B);
}

// Round 10
// 248.853 us; speedup vs baseline: 1.3853x; 1.3853x over previous
//
#include <hip/hip_runtime.h>
#include <hip/hip_bf16.h>

// NeRF coarse renderer. Layer 2 on bf16 MFMA:
//   rows 0-47:  h2 = Ah*Bh                 (1-term, err ~sqrt2*2^-9, rgb-smooth path)
//   rows 48-63: h2 = Ah*(Bh+Bl) + Al*Bh    (3-term — sample 63 feeds the
//                                           alpha = 1-exp(-1e10*relu(sigma)) STEP)
// Layer 3 on MFMA (wave-K-split, W3 B-frag cols 0-3 real), per-wave partials
// materialized in comb[8][64][4], summed in phase 5 (no LDS atomics).
// sigma_63 recomputed exactly from f32-staged h2 row 63 (f32 W3).
// 1 ray/block, LDS 41 KiB => 3 blocks/CU; launch_bounds(512,6) so the register
// file is NOT capped (round-9 lesson: (512,8) => 64 VGPR/wave => spills).
//
// d_in: 0 near(B,1) 1 far(B,1) 2 center(B,3) 3 dir(B,3)
//       4 W1(3,256) 5 b1(256) 6 W2(256,256) 7 b2(256) 8 W3(256,4) 9 b3(4)
// d_out: [rgb (B,3) | depth (B) | weights (B,64) | sigmas_last (B)] f32
// d_ws: W2 repacked as MFMA B-fragments, bf16 hi[64K] + lo[64K] (256 KiB).

constexpr int H  = 256;
constexpr int KS = 64;     // samples per ray = M rows per block

typedef __attribute__((ext_vector_type(8))) short short8;           // 8 bf16
typedef __attribute__((ext_vector_type(4))) float f32x4;            // C/D frag

__device__ __forceinline__ f32x4 mfma16(short8 a, short8 b, f32x4 c) {
    return __builtin_amdgcn_mfma_f32_16x16x32_bf16(a, b, c, 0, 0, 0);
}
__device__ __forceinline__ void split_bf16(float x, short& hi, short& lo) {
    __hip_bfloat16 h = __float2bfloat16(x);
    float hf = __bfloat162float(h);
    __hip_bfloat16 l = __float2bfloat16(x - hf);
    union { __hip_bfloat16 b; short s; } c1, c2;
    c1.b = h; c2.b = l;
    hi = c1.s; lo = c2.s;
}
__device__ __forceinline__ unsigned short f2bf(float x) {
    union { __hip_bfloat16 b; unsigned short s; } c;
    c.b = __float2bfloat16(x);
    return c.s;
}
__device__ __forceinline__ float bf2f(unsigned short s) {
    union { unsigned int u; float f; } c;
    c.u = ((unsigned int)s) << 16;
    return c.f;
}

// ---- pre-pass: pack W2 (f32 row-major [k][n]) into frag-ordered bf16 hi/lo.
// Element i = ((ks*16 + ntg)*64 + lane)*8 + e  maps to
//   k = ks*32 + (lane>>4)*8 + e,  n = ntg*16 + (lane&15).
__global__ void pack_w2_kernel(const float* __restrict__ W2,
                               unsigned short* __restrict__ hi,
                               unsigned short* __restrict__ lo)
{
    const int i  = blockIdx.x * 256 + threadIdx.x;   // 0..65535
    const int e  = i & 7;
    const int l  = (i >> 3) & 63;
    const int nt = (i >> 9) & 15;
    const int ks = i >> 13;
    const int k  = ks * 32 + (l >> 4) * 8 + e;
    const int n  = nt * 16 + (l & 15);
    short h, lw;
    split_bf16(W2[k * H + n], h, lw);
    hi[i] = (unsigned short)h;
    lo[i] = (unsigned short)lw;
}

// LDS, lifetime-aliased, ~41 KiB => 3 blocks/CU:
//   big (32 KiB): ah A-frags (ph1->ph2)  ALIASES  h2f layer-3 A-frags (ph3->ph4)
//   r2  ( 9 KiB): al3 lo A-frags mt3 (ph1->ph2)  ALIASES  comb[8][64][4]+row63 (ph3->ph5)
struct R2a { unsigned short al3[8 * 64 * 8]; };              // 8 KiB
struct R2b { float comb[8][KS][4]; float row63[H]; };        // 8 KiB + 1 KiB
union  R2  { R2a a; R2b b; };
struct SM {
    union { unsigned short ah[8 * 4 * 64 * 8];
            unsigned short h2f[8 * 4 * 64 * 8]; } big;       // 32 KiB
    R2 r2;                                                   //  9 KiB
};

__launch_bounds__(512, 6)
__global__ void nerf_mfma_kernel(
    const float* __restrict__ g_near, const float* __restrict__ g_far,
    const float* __restrict__ g_center, const float* __restrict__ g_dir,
    const float* __restrict__ W1, const float* __restrict__ b1,
    const float* __restrict__ b2,
    const float* __restrict__ W3, const float* __restrict__ b3,
    const unsigned short* __restrict__ w2h, const unsigned short* __restrict__ w2l,
    float* __restrict__ out, int B)
{
    __shared__ __align__(16) SM sm;

    const int t    = threadIdx.x;
    const int lane = t & 63;
    const int wv   = __builtin_amdgcn_readfirstlane(t >> 6);   // 0..7
    const int r    = blockIdx.x;                               // ray id

    // ---- ray params (block-uniform scalar loads) ----
    const float nr = g_near[r], fa = g_far[r];
    const float cx = g_center[r*3+0], cy = g_center[r*3+1], cz = g_center[r*3+2];
    const float dx = g_dir[r*3+0],    dy = g_dir[r*3+1],    dz = g_dir[r*3+2];

    // ---- phase 1: layer 1 (f32, points recomputed in-register);
    //      h1 -> bf16 A-frags (hi; +lo for mt==3) ----
    {
        const int kbase = wv * 32 + (lane >> 4) * 8;   // 8 consecutive k
        float w1r[3][8], b1r[8];
        #pragma unroll
        for (int c = 0; c < 3; ++c) {
            const f32x4 a = *(const f32x4*)&W1[c * H + kbase];
            const f32x4 b = *(const f32x4*)&W1[c * H + kbase + 4];
            #pragma unroll
            for (int e = 0; e < 4; ++e) { w1r[c][e] = a[e]; w1r[c][e+4] = b[e]; }
        }
        {
            const f32x4 a = *(const f32x4*)&b1[kbase];
            const f32x4 b = *(const f32x4*)&b1[kbase + 4];
            #pragma unroll
            for (int e = 0; e < 4; ++e) { b1r[e] = a[e]; b1r[e+4] = b[e]; }
        }
        const int prow = lane & 15;
        #pragma unroll
        for (int mt = 0; mt < 4; ++mt) {
            const int srow = mt * 16 + prow;
            const float uu = (float)srow * (1.0f / 63.0f);
            const float z  = nr * (1.0f - uu) + fa * uu;
            const float px = cx + z * dx, py = cy + z * dy, pz = cz + z * dz;
            short8 hv, lv;
            #pragma unroll
            for (int e = 0; e < 8; ++e) {
                float x = fmaf(px, w1r[0][e],
                          fmaf(py, w1r[1][e],
                          fmaf(pz, w1r[2][e], b1r[e])));
                x = fmaxf(x, 0.0f);
                const unsigned short hb = f2bf(x);
                hv[e] = (short)hb;
                if (mt == 3) lv[e] = (short)f2bf(x - bf2f(hb));
            }
            *(short8*)&sm.big.ah[((wv * 4 + mt) * 64 + lane) * 8] = hv;
            if (mt == 3) *(short8*)&sm.r2.a.al3[(wv * 64 + lane) * 8] = lv;
        }
    }
    __syncthreads();

    // ---- phase 2: layer 2 GEMM via MFMA (1-term; mt3 = 3-term) ----
    f32x4 acc[4][2];
    #pragma unroll
    for (int mt = 0; mt < 4; ++mt) {
        acc[mt][0] = (f32x4){0.f,0.f,0.f,0.f};
        acc[mt][1] = (f32x4){0.f,0.f,0.f,0.f};
    }
    {
        const int ntg0 = wv * 2, ntg1 = ntg0 + 1;
        const short8* Bh = (const short8*)w2h;
        const short8* Bl = (const short8*)w2l;
        const short8* Ah = (const short8*)sm.big.ah;
        const short8* Al = (const short8*)sm.r2.a.al3;
        __builtin_amdgcn_s_setprio(1);
        #pragma unroll 2
        for (int ks = 0; ks < 8; ++ks) {
            const short8 b0h  = Bh[(ks * 16 + ntg0) * 64 + lane];
            const short8 b1h_ = Bh[(ks * 16 + ntg1) * 64 + lane];
            #pragma unroll
            for (int mt = 0; mt < 4; ++mt) {
                const short8 ah = Ah[(ks * 4 + mt) * 64 + lane];
                f32x4 c0 = acc[mt][0], c1 = acc[mt][1];
                c0 = mfma16(ah, b0h, c0);
                c1 = mfma16(ah, b1h_, c1);
                if (mt == 3) {               // sigma-critical rows: full 3-term
                    const short8 b0l = Bl[(ks * 16 + ntg0) * 64 + lane];
                    const short8 b1l = Bl[(ks * 16 + ntg1) * 64 + lane];
                    const short8 al  = Al[ks * 64 + lane];
                    c0 = mfma16(ah, b0l, c0);
                    c0 = mfma16(al, b0h, c0);
                    c1 = mfma16(ah, b1l, c1);
                    c1 = mfma16(al, b1h_, c1);
                }
                acc[mt][0] = c0; acc[mt][1] = c1;
            }
        }
        __builtin_amdgcn_s_setprio(0);
    }
    __syncthreads();   // ah/al3 dead; big->h2f, r2->comb/row63 reuse is now safe

    // ---- phase 3: +b2, ReLU; h2 -> bf16 A-frag order; row 63 f32 ----
    {
        const int c0 = wv * 32 + (lane & 15);
        const int c1 = c0 + 16;
        const float b2c0 = b2[c0], b2c1 = b2[c1];
        const int rlow = (lane >> 4) * 4;
        const int jj0 = lane & 15, jj1 = jj0 + 16;
        const bool lastGrp = ((lane >> 4) == 3);
        #pragma unroll
        for (int mt = 0; mt < 4; ++mt) {
            const f32x4 v0 = acc[mt][0], v1 = acc[mt][1];
            #pragma unroll
            for (int q = 0; q < 4; ++q) {
                const float a0 = fmaxf(v0[q] + b2c0, 0.0f);
                const float a1 = fmaxf(v1[q] + b2c1, 0.0f);
                const int l20 = ((jj0 >> 3) << 4) | (rlow + q);
                const int l21 = ((jj1 >> 3) << 4) | (rlow + q);
                sm.big.h2f[((wv * 4 + mt) * 64 + l20) * 8 + (jj0 & 7)] = f2bf(a0);
                sm.big.h2f[((wv * 4 + mt) * 64 + l21) * 8 + (jj1 & 7)] = f2bf(a1);
                if (mt == 3 && lastGrp && q == 3) {
                    sm.r2.b.row63[c0] = a0; sm.r2.b.row63[c1] = a1;
                }
            }
        }
    }
    __syncthreads();

    // ---- phase 4: layer 3 via MFMA, K-split across waves -> comb[wv] ----
    {
        // W3 B-frag on the fly: k = wv*32 + (lane>>4)*8 + e, n = lane&15 (<4 real)
        const int n = lane & 15;
        short8 bw3;
        #pragma unroll
        for (int e = 0; e < 8; ++e) {
            const int k = wv * 32 + (lane >> 4) * 8 + e;
            const float v = (n < 4) ? W3[k * 4 + n] : 0.0f;
            bw3[e] = (short)f2bf(v);
        }
        const short8* Ah2 = (const short8*)sm.big.h2f;
        #pragma unroll
        for (int mt = 0; mt < 4; ++mt) {
            const short8 a = Ah2[(wv * 4 + mt) * 64 + lane];
            f32x4 d = (f32x4){0.f,0.f,0.f,0.f};
            d = mfma16(a, bw3, d);
            if (n < 4) {
                #pragma unroll
                for (int q = 0; q < 4; ++q)
                    sm.r2.b.comb[wv][mt * 16 + (lane >> 4) * 4 + q][n] = d[q];
            }
        }
    }
    __syncthreads();

    // ---- phase 5: volume rendering (wave 0, lane = sample) ----
    if (t < KS) {
        const int s = t;

        // exact sigma for sample 63: all 64 lanes cooperate on the 256-dot
        float sp = 0.f;
        #pragma unroll
        for (int q = 0; q < 4; ++q) {
            const int j = s * 4 + q;
            sp = fmaf(sm.r2.b.row63[j], W3[j * 4 + 3], sp);
        }
        #pragma unroll
        for (int off = 32; off > 0; off >>= 1) sp += __shfl_xor(sp, off, 64);
        const float sig63 = sp + b3[3];

        f32x4 oo = (f32x4){0.f,0.f,0.f,0.f};
        #pragma unroll
        for (int q = 0; q < 8; ++q) {
            const f32x4 c = *(const f32x4*)&sm.r2.b.comb[q][s][0];
            oo[0] += c[0]; oo[1] += c[1]; oo[2] += c[2]; oo[3] += c[3];
        }
        const float o0 = oo[0] + b3[0];
        const float o1 = oo[1] + b3[1];
        const float o2 = oo[2] + b3[2];
        const float sigma = (s == 63) ? sig63 : (oo[3] + b3[3]);

        const float uu = (float)s * (1.0f / 63.0f);
        const float z  = nr * (1.0f - uu) + fa * uu;
        const float u2 = (float)(s + 1) * (1.0f / 63.0f);
        const float z2 = nr * (1.0f - u2) + fa * u2;
        const float delta = (s == 63) ? 1e10f : (z2 - z);
        const float alpha = 1.0f - __expf(-delta * fmaxf(sigma, 0.0f));

        // exclusive product scan of (1 - alpha + eps)
        float P = 1.0f - alpha + 1e-8f;
        #pragma unroll
        for (int off = 1; off < 64; off <<= 1) {
            const float v = __shfl_up(P, off, 64);
            if (s >= off) P *= v;
        }
        float T = __shfl_up(P, 1, 64);
        if (s == 0) T = 1.0f;
        const float w = alpha * T;

        out[(size_t)B * 4 + (size_t)r * 64 + s] = w;

        float ws = w, dep = w * z, q0 = w * o0, q1 = w * o1, q2 = w * o2;
        #pragma unroll
        for (int off = 32; off > 0; off >>= 1) {
            ws  += __shfl_xor(ws,  off, 64);
            dep += __shfl_xor(dep, off, 64);
            q0  += __shfl_xor(q0,  off, 64);
            q1  += __shfl_xor(q1,  off, 64);
            q2  += __shfl_xor(q2,  off, 64);
        }
        if (s == 0) {
            out[(size_t)r * 3 + 0] = q0 + 1.0f - ws;
            out[(size_t)r * 3 + 1] = q1 + 1.0f - ws;
            out[(size_t)r * 3 + 2] = q2 + 1.0f - ws;
            out[(size_t)B * 3 + r] = dep;
            out[(size_t)B * 68 + r] = sig63;
        }
    }
}

extern "C" void kernel_launch(void* const* d_in, const int* in_sizes, int n_in,
                              void* d_out, int out_size, void* d_ws, size_t ws_size,
                              hipStream_t stream)
{
    const int B = in_sizes[0];
    if (ws_size < (size_t)(2 * 65536 * sizeof(unsigned short))) return;  // need 256 KiB

    unsigned short* w2h = (unsigned short*)d_ws;
    unsigned short* w2l = w2h + 65536;

    pack_w2_kernel<<<256, 256, 0, stream>>>((const float*)d_in[6], w2h, w2l);

    nerf_mfma_kernel<<<B, 512, 0, stream>>>(
        (const float*)d_in[0], (const float*)d_in[1],
        (const float*)d_in[2], (const float*)d_in[3],
        (const float*)d_in[4], (const float*)d_in[5],
        (const float*)d_in[7],
        (const float*)d_in[8], (const float*)d_in[9],
        w2h, w2l,
        (float*)d_out, B);
}

// Round 11
// 243.888 us; speedup vs baseline: 1.4135x; 1.0204x over previous
//
#include <hip/hip_runtime.h>
#include <hip/hip_bf16.h>

// NeRF coarse renderer. Layer 2 on bf16 MFMA:
//   rows 0-47:  h2 = Ah*Bh                 (1-term, err ~sqrt2*2^-9, rgb-smooth path)
//   rows 48-63: h2 = Ah*(Bh+Bl) + Al*Bh    (3-term — sample 63 feeds the
//                                           alpha = 1-exp(-1e10*relu(sigma)) STEP)
// Layer 3 on MFMA (wave-K-split, W3 B-frag cols 0-3 real), per-wave partials in
// comb[8][64][4]. sigma_63 stays f32-exact: phase 3's row-63 threads compute
// per-wave f32 partial dots and store them in comb[wv][63][3] (slot unused by
// the bf16 path — phase 4 skips it), so phase 5's 8-way sum yields f32 sigma63.
// 1 ray/block, LDS = 40960 B EXACTLY => 4 blocks/CU; launch_bounds(512,8)
// (VGPR need is 40 < 64 cap, no atomics — r9's two stall sources removed).
//
// d_in: 0 near(B,1) 1 far(B,1) 2 center(B,3) 3 dir(B,3)
//       4 W1(3,256) 5 b1(256) 6 W2(256,256) 7 b2(256) 8 W3(256,4) 9 b3(4)
// d_out: [rgb (B,3) | depth (B) | weights (B,64) | sigmas_last (B)] f32
// d_ws: W2 repacked as MFMA B-fragments, bf16 hi[64K] + lo[64K] (256 KiB).

constexpr int H  = 256;
constexpr int KS = 64;     // samples per ray = M rows per block

typedef __attribute__((ext_vector_type(8))) short short8;           // 8 bf16
typedef __attribute__((ext_vector_type(4))) float f32x4;            // C/D frag

__device__ __forceinline__ f32x4 mfma16(short8 a, short8 b, f32x4 c) {
    return __builtin_amdgcn_mfma_f32_16x16x32_bf16(a, b, c, 0, 0, 0);
}
__device__ __forceinline__ void split_bf16(float x, short& hi, short& lo) {
    __hip_bfloat16 h = __float2bfloat16(x);
    float hf = __bfloat162float(h);
    __hip_bfloat16 l = __float2bfloat16(x - hf);
    union { __hip_bfloat16 b; short s; } c1, c2;
    c1.b = h; c2.b = l;
    hi = c1.s; lo = c2.s;
}
__device__ __forceinline__ unsigned short f2bf(float x) {
    union { __hip_bfloat16 b; unsigned short s; } c;
    c.b = __float2bfloat16(x);
    return c.s;
}
__device__ __forceinline__ float bf2f(unsigned short s) {
    union { unsigned int u; float f; } c;
    c.u = ((unsigned int)s) << 16;
    return c.f;
}

// ---- pre-pass: pack W2 (f32 row-major [k][n]) into frag-ordered bf16 hi/lo.
// Element i = ((ks*16 + ntg)*64 + lane)*8 + e  maps to
//   k = ks*32 + (lane>>4)*8 + e,  n = ntg*16 + (lane&15).
__global__ void pack_w2_kernel(const float* __restrict__ W2,
                               unsigned short* __restrict__ hi,
                               unsigned short* __restrict__ lo)
{
    const int i  = blockIdx.x * 256 + threadIdx.x;   // 0..65535
    const int e  = i & 7;
    const int l  = (i >> 3) & 63;
    const int nt = (i >> 9) & 15;
    const int ks = i >> 13;
    const int k  = ks * 32 + (l >> 4) * 8 + e;
    const int n  = nt * 16 + (l & 15);
    short h, lw;
    split_bf16(W2[k * H + n], h, lw);
    hi[i] = (unsigned short)h;
    lo[i] = (unsigned short)lw;
}

// LDS, lifetime-aliased, 40960 B total => 4 blocks/CU:
//   big (32 KiB): ah A-frags (ph1->ph2)  ALIASES  h2f layer-3 A-frags (ph3->ph4)
//   r2  ( 8 KiB): al3 lo A-frags mt3 (ph1->ph2)  ALIASES  comb[8][64][4] (ph3->ph5)
struct R2a { unsigned short al3[8 * 64 * 8]; };              // 8 KiB
struct R2b { float comb[8][KS][4]; };                        // 8 KiB
union  R2  { R2a a; R2b b; };
struct SM {
    union { unsigned short ah[8 * 4 * 64 * 8];
            unsigned short h2f[8 * 4 * 64 * 8]; } big;       // 32 KiB
    R2 r2;                                                   //  8 KiB
};

__launch_bounds__(512, 8)
__global__ void nerf_mfma_kernel(
    const float* __restrict__ g_near, const float* __restrict__ g_far,
    const float* __restrict__ g_center, const float* __restrict__ g_dir,
    const float* __restrict__ W1, const float* __restrict__ b1,
    const float* __restrict__ b2,
    const float* __restrict__ W3, const float* __restrict__ b3,
    const unsigned short* __restrict__ w2h, const unsigned short* __restrict__ w2l,
    float* __restrict__ out, int B)
{
    __shared__ __align__(16) SM sm;

    const int t    = threadIdx.x;
    const int lane = t & 63;
    const int wv   = __builtin_amdgcn_readfirstlane(t >> 6);   // 0..7
    const int r    = blockIdx.x;                               // ray id

    // ---- ray params (block-uniform scalar loads) ----
    const float nr = g_near[r], fa = g_far[r];
    const float cx = g_center[r*3+0], cy = g_center[r*3+1], cz = g_center[r*3+2];
    const float dx = g_dir[r*3+0],    dy = g_dir[r*3+1],    dz = g_dir[r*3+2];

    // ---- phase 1: layer 1 (f32, points recomputed in-register);
    //      h1 -> bf16 A-frags (hi; +lo for mt==3) ----
    {
        const int kbase = wv * 32 + (lane >> 4) * 8;   // 8 consecutive k
        float w1r[3][8], b1r[8];
        #pragma unroll
        for (int c = 0; c < 3; ++c) {
            const f32x4 a = *(const f32x4*)&W1[c * H + kbase];
            const f32x4 b = *(const f32x4*)&W1[c * H + kbase + 4];
            #pragma unroll
            for (int e = 0; e < 4; ++e) { w1r[c][e] = a[e]; w1r[c][e+4] = b[e]; }
        }
        {
            const f32x4 a = *(const f32x4*)&b1[kbase];
            const f32x4 b = *(const f32x4*)&b1[kbase + 4];
            #pragma unroll
            for (int e = 0; e < 4; ++e) { b1r[e] = a[e]; b1r[e+4] = b[e]; }
        }
        const int prow = lane & 15;
        #pragma unroll
        for (int mt = 0; mt < 4; ++mt) {
            const int srow = mt * 16 + prow;
            const float uu = (float)srow * (1.0f / 63.0f);
            const float z  = nr * (1.0f - uu) + fa * uu;
            const float px = cx + z * dx, py = cy + z * dy, pz = cz + z * dz;
            short8 hv, lv;
            #pragma unroll
            for (int e = 0; e < 8; ++e) {
                float x = fmaf(px, w1r[0][e],
                          fmaf(py, w1r[1][e],
                          fmaf(pz, w1r[2][e], b1r[e])));
                x = fmaxf(x, 0.0f);
                const unsigned short hb = f2bf(x);
                hv[e] = (short)hb;
                if (mt == 3) lv[e] = (short)f2bf(x - bf2f(hb));
            }
            *(short8*)&sm.big.ah[((wv * 4 + mt) * 64 + lane) * 8] = hv;
            if (mt == 3) *(short8*)&sm.r2.a.al3[(wv * 64 + lane) * 8] = lv;
        }
    }
    __syncthreads();

    // ---- phase 2: layer 2 GEMM via MFMA (1-term; mt3 = 3-term) ----
    f32x4 acc[4][2];
    #pragma unroll
    for (int mt = 0; mt < 4; ++mt) {
        acc[mt][0] = (f32x4){0.f,0.f,0.f,0.f};
        acc[mt][1] = (f32x4){0.f,0.f,0.f,0.f};
    }
    {
        const int ntg0 = wv * 2, ntg1 = ntg0 + 1;
        const short8* Bh = (const short8*)w2h;
        const short8* Bl = (const short8*)w2l;
        const short8* Ah = (const short8*)sm.big.ah;
        const short8* Al = (const short8*)sm.r2.a.al3;
        __builtin_amdgcn_s_setprio(1);
        #pragma unroll 2
        for (int ks = 0; ks < 8; ++ks) {
            const short8 b0h  = Bh[(ks * 16 + ntg0) * 64 + lane];
            const short8 b1h_ = Bh[(ks * 16 + ntg1) * 64 + lane];
            #pragma unroll
            for (int mt = 0; mt < 4; ++mt) {
                const short8 ah = Ah[(ks * 4 + mt) * 64 + lane];
                f32x4 c0 = acc[mt][0], c1 = acc[mt][1];
                c0 = mfma16(ah, b0h, c0);
                c1 = mfma16(ah, b1h_, c1);
                if (mt == 3) {               // sigma-critical rows: full 3-term
                    const short8 b0l = Bl[(ks * 16 + ntg0) * 64 + lane];
                    const short8 b1l = Bl[(ks * 16 + ntg1) * 64 + lane];
                    const short8 al  = Al[ks * 64 + lane];
                    c0 = mfma16(ah, b0l, c0);
                    c0 = mfma16(al, b0h, c0);
                    c1 = mfma16(ah, b1l, c1);
                    c1 = mfma16(al, b1h_, c1);
                }
                acc[mt][0] = c0; acc[mt][1] = c1;
            }
        }
        __builtin_amdgcn_s_setprio(0);
    }
    __syncthreads();   // ah/al3 dead; big->h2f, r2->comb reuse is now safe

    // ---- phase 3: +b2, ReLU; h2 -> bf16 A-frag order;
    //      f32 sigma63 wave-partials -> comb[wv][63][3] ----
    {
        const int c0 = wv * 32 + (lane & 15);
        const int c1 = c0 + 16;
        const float b2c0 = b2[c0], b2c1 = b2[c1];
        const float w3c0 = W3[c0 * 4 + 3], w3c1 = W3[c1 * 4 + 3];
        const int rlow = (lane >> 4) * 4;
        const int jj0 = lane & 15, jj1 = jj0 + 16;
        const bool lastGrp = ((lane >> 4) == 3);
        float r63a = 0.f, r63b = 0.f;   // f32 h2[63][c0], h2[63][c1] (lastGrp lanes)
        #pragma unroll
        for (int mt = 0; mt < 4; ++mt) {
            const f32x4 v0 = acc[mt][0], v1 = acc[mt][1];
            #pragma unroll
            for (int q = 0; q < 4; ++q) {
                const float a0 = fmaxf(v0[q] + b2c0, 0.0f);
                const float a1 = fmaxf(v1[q] + b2c1, 0.0f);
                const int l20 = ((jj0 >> 3) << 4) | (rlow + q);
                const int l21 = ((jj1 >> 3) << 4) | (rlow + q);
                sm.big.h2f[((wv * 4 + mt) * 64 + l20) * 8 + (jj0 & 7)] = f2bf(a0);
                sm.big.h2f[((wv * 4 + mt) * 64 + l21) * 8 + (jj1 & 7)] = f2bf(a1);
                if (mt == 3 && q == 3) { r63a = a0; r63b = a1; }
            }
        }
        if (lastGrp) {   // lanes 48-63 hold row 63; reduce their f32 partial dot
            float p = fmaf(r63a, w3c0, r63b * w3c1);
            #pragma unroll
            for (int off = 1; off < 16; off <<= 1) p += __shfl_xor(p, off, 64);
            if ((lane & 15) == 0) sm.r2.b.comb[wv][63][3] = p;
        }
    }
    __syncthreads();

    // ---- phase 4: layer 3 via MFMA, K-split across waves -> comb[wv] ----
    {
        // W3 B-frag on the fly: k = wv*32 + (lane>>4)*8 + e, n = lane&15 (<4 real)
        const int n = lane & 15;
        short8 bw3;
        #pragma unroll
        for (int e = 0; e < 8; ++e) {
            const int k = wv * 32 + (lane >> 4) * 8 + e;
            const float v = (n < 4) ? W3[k * 4 + n] : 0.0f;
            bw3[e] = (short)f2bf(v);
        }
        const short8* Ah2 = (const short8*)sm.big.h2f;
        #pragma unroll
        for (int mt = 0; mt < 4; ++mt) {
            const short8 a = Ah2[(wv * 4 + mt) * 64 + lane];
            f32x4 d = (f32x4){0.f,0.f,0.f,0.f};
            d = mfma16(a, bw3, d);
            if (n < 4) {
                #pragma unroll
                for (int q = 0; q < 4; ++q) {
                    // skip [63][3]: holds the f32 sigma63 partial from phase 3
                    if (!(mt == 3 && q == 3 && n == 3 && (lane >> 4) == 3))
                        sm.r2.b.comb[wv][mt * 16 + (lane >> 4) * 4 + q][n] = d[q];
                }
            }
        }
    }
    __syncthreads();

    // ---- phase 5: volume rendering (wave 0, lane = sample) ----
    if (t < KS) {
        const int s = t;

        f32x4 oo = (f32x4){0.f,0.f,0.f,0.f};
        #pragma unroll
        for (int q = 0; q < 8; ++q) {
            const f32x4 c = *(const f32x4*)&sm.r2.b.comb[q][s][0];
            oo[0] += c[0]; oo[1] += c[1]; oo[2] += c[2]; oo[3] += c[3];
        }
        const float o0 = oo[0] + b3[0];
        const float o1 = oo[1] + b3[1];
        const float o2 = oo[2] + b3[2];
        const float sigma = oo[3] + b3[3];   // s=63: f32-exact via comb[*][63][3]

        const float uu = (float)s * (1.0f / 63.0f);
        const float z  = nr * (1.0f - uu) + fa * uu;
        const float u2 = (float)(s + 1) * (1.0f / 63.0f);
        const float z2 = nr * (1.0f - u2) + fa * u2;
        const float delta = (s == 63) ? 1e10f : (z2 - z);
        const float alpha = 1.0f - __expf(-delta * fmaxf(sigma, 0.0f));

        // exclusive product scan of (1 - alpha + eps)
        float P = 1.0f - alpha + 1e-8f;
        #pragma unroll
        for (int off = 1; off < 64; off <<= 1) {
            const float v = __shfl_up(P, off, 64);
            if (s >= off) P *= v;
        }
        float T = __shfl_up(P, 1, 64);
        if (s == 0) T = 1.0f;
        const float w = alpha * T;

        out[(size_t)B * 4 + (size_t)r * 64 + s] = w;

        float ws = w, dep = w * z, q0 = w * o0, q1 = w * o1, q2 = w * o2;
        #pragma unroll
        for (int off = 32; off > 0; off >>= 1) {
            ws  += __shfl_xor(ws,  off, 64);
            dep += __shfl_xor(dep, off, 64);
            q0  += __shfl_xor(q0,  off, 64);
            q1  += __shfl_xor(q1,  off, 64);
            q2  += __shfl_xor(q2,  off, 64);
        }
        const float sl = __shfl(sigma, 63, 64);
        if (s == 0) {
            out[(size_t)r * 3 + 0] = q0 + 1.0f - ws;
            out[(size_t)r * 3 + 1] = q1 + 1.0f - ws;
            out[(size_t)r * 3 + 2] = q2 + 1.0f - ws;
            out[(size_t)B * 3 + r] = dep;
            out[(size_t)B * 68 + r] = sl;
        }
    }
}

extern "C" void kernel_launch(void* const* d_in, const int* in_sizes, int n_in,
                              void* d_out, int out_size, void* d_ws, size_t ws_size,
                              hipStream_t stream)
{
    const int B = in_sizes[0];
    if (ws_size < (size_t)(2 * 65536 * sizeof(unsigned short))) return;  // need 256 KiB

    unsigned short* w2h = (unsigned short*)d_ws;
    unsigned short* w2l = w2h + 65536;

    pack_w2_kernel<<<256, 256, 0, stream>>>((const float*)d_in[6], w2h, w2l);

    nerf_mfma_kernel<<<B, 512, 0, stream>>>(
        (const float*)d_in[0], (const float*)d_in[1],
        (const float*)d_in[2], (const float*)d_in[3],
        (const float*)d_in[4], (const float*)d_in[5],
        (const float*)d_in[7],
        (const float*)d_in[8], (const float*)d_in[9],
        w2h, w2l,
        (float*)d_out, B);
}